// Round 1
// baseline (1920.311 us; speedup 1.0000x reference)
//
#include <hip/hip_runtime.h>

#define N_RID  100000
#define N_CELL 400000
#define NCOLS  4
#define NE     100000
#define D      64

// ---------------------------------------------------------------- degree
__global__ void deg_kernel(const int* __restrict__ dst, float* __restrict__ deg,
                           int n_dst) {
    int t = blockIdx.x * 256 + threadIdx.x;
    if (t >= NCOLS * NE) return;
    int c = t / NE;
    int d = dst[t];
    atomicAdd(&deg[(size_t)c * n_dst + d], 1.0f);
}

// ------------------------------------------------- y = (h - mu) @ W_c  (4 relations)
// block = 256 (4 waves). wave c handles relation c; lane j holds W_c[:,j] in regs.
__global__ void __launch_bounds__(256) y_gemm(const float* __restrict__ h,
        const float* __restrict__ W, const float* __restrict__ mu,
        float* __restrict__ y, int nrows) {
    __shared__ float hlds[64 * D];
    const int wave = threadIdx.x >> 6;
    const int lane = threadIdx.x & 63;
    float w[D];
#pragma unroll
    for (int k = 0; k < D; ++k) w[k] = W[(wave * D + k) * D + lane];

    int row0 = blockIdx.x * 64;
    int nr = min(64, nrows - row0);
    for (int i = threadIdx.x; i < nr * 16; i += 256) {
        int r = i >> 4, q = i & 15;
        float4 v = reinterpret_cast<const float4*>(h + (size_t)(row0 + r) * D)[q];
        if (mu) {
            float4 m = reinterpret_cast<const float4*>(mu)[q];
            v.x -= m.x; v.y -= m.y; v.z -= m.z; v.w -= m.w;
        }
        reinterpret_cast<float4*>(hlds + r * D)[q] = v;
    }
    __syncthreads();
    for (int r = 0; r < nr; ++r) {
        const float4* hr = reinterpret_cast<const float4*>(hlds + r * D);
        float acc = 0.f;
#pragma unroll
        for (int k4 = 0; k4 < 16; ++k4) {
            float4 v = hr[k4];
            acc = fmaf(v.x, w[4 * k4 + 0], acc);
            acc = fmaf(v.y, w[4 * k4 + 1], acc);
            acc = fmaf(v.z, w[4 * k4 + 2], acc);
            acc = fmaf(v.w, w[4 * k4 + 3], acc);
        }
        y[((size_t)wave * nrows + row0 + r) * D + lane] = acc;
    }
}

// -------------------------------- out[n] = bbar + 0.25*sum_c scale_c[n]*((h[n]-mu)@W_c)
#define TILE_SC 32
__global__ void __launch_bounds__(256) self_cell(const float* __restrict__ h,
        const float* __restrict__ deg, const float* __restrict__ W,
        const float* __restrict__ bias, const float* __restrict__ mu,
        float* __restrict__ out, int nrows) {
    __shared__ float hlds[TILE_SC * D];
    __shared__ float part[4][TILE_SC * D];
    __shared__ float sc[4][TILE_SC];
    const int wave = threadIdx.x >> 6;
    const int lane = threadIdx.x & 63;
    int row0 = blockIdx.x * TILE_SC;   // nrows divisible by 32

    for (int i = threadIdx.x; i < TILE_SC * 16; i += 256) {
        int r = i >> 4, q = i & 15;
        float4 v = reinterpret_cast<const float4*>(h + (size_t)(row0 + r) * D)[q];
        if (mu) {
            float4 m = reinterpret_cast<const float4*>(mu)[q];
            v.x -= m.x; v.y -= m.y; v.z -= m.z; v.w -= m.w;
        }
        reinterpret_cast<float4*>(hlds + r * D)[q] = v;
    }
    if (threadIdx.x < 4 * TILE_SC) {
        int c = threadIdx.x >> 5, r = threadIdx.x & 31;
        sc[c][r] = 1.0f / (deg[(size_t)c * nrows + row0 + r] + 1.0f);
    }
    float w[D];
#pragma unroll
    for (int k = 0; k < D; ++k) w[k] = W[(wave * D + k) * D + lane];
    __syncthreads();

    for (int r = 0; r < TILE_SC; ++r) {
        const float4* hr = reinterpret_cast<const float4*>(hlds + r * D);
        float acc = 0.f;
#pragma unroll
        for (int k4 = 0; k4 < 16; ++k4) {
            float4 v = hr[k4];
            acc = fmaf(v.x, w[4 * k4 + 0], acc);
            acc = fmaf(v.y, w[4 * k4 + 1], acc);
            acc = fmaf(v.z, w[4 * k4 + 2], acc);
            acc = fmaf(v.w, w[4 * k4 + 3], acc);
        }
        part[wave][r * D + lane] = sc[wave][r] * acc;
    }
    __syncthreads();
    for (int i = threadIdx.x; i < TILE_SC * D; i += 256) {
        int j = i & 63;
        float b = 0.25f * (bias[j] + bias[64 + j] + bias[128 + j] + bias[192 + j]);
        out[(size_t)row0 * D + i] =
            0.25f * (part[0][i] + part[1][i] + part[2][i] + part[3][i]) + b;
    }
}

// ------------- out[n] = bbar + 0.25*sum_c scale_c[n]*((agg_c[n] + h[n]-mu)@W_c)
#define TILE_FR 16
__global__ void __launch_bounds__(256) fused_rid(const float* __restrict__ h,
        const float* __restrict__ agg, const float* __restrict__ deg,
        const float* __restrict__ W, const float* __restrict__ bias,
        const float* __restrict__ mu, float* __restrict__ out, int nrows) {
    __shared__ float hlds[TILE_FR * D];
    __shared__ float alds[4][TILE_FR * D];
    __shared__ float part[4][TILE_FR * D];
    __shared__ float sc[4][TILE_FR];
    const int wave = threadIdx.x >> 6;
    const int lane = threadIdx.x & 63;
    int row0 = blockIdx.x * TILE_FR;   // nrows divisible by 16

    for (int i = threadIdx.x; i < TILE_FR * 16; i += 256) {
        int r = i >> 4, q = i & 15;
        float4 v = reinterpret_cast<const float4*>(h + (size_t)(row0 + r) * D)[q];
        if (mu) {
            float4 m = reinterpret_cast<const float4*>(mu)[q];
            v.x -= m.x; v.y -= m.y; v.z -= m.z; v.w -= m.w;
        }
        reinterpret_cast<float4*>(hlds + r * D)[q] = v;
    }
    for (int i = threadIdx.x; i < 4 * TILE_FR * 16; i += 256) {
        int c = i >> 8, rem = i & 255;       // TILE_FR*16 == 256
        int r = rem >> 4, q = rem & 15;
        float4 v = reinterpret_cast<const float4*>(
            agg + ((size_t)c * nrows + row0 + r) * D)[q];
        reinterpret_cast<float4*>(alds[c] + r * D)[q] = v;
    }
    if (threadIdx.x < 4 * TILE_FR) {
        int c = threadIdx.x >> 4, r = threadIdx.x & 15;
        sc[c][r] = 1.0f / (deg[(size_t)c * nrows + row0 + r] + 1.0f);
    }
    float w[D];
#pragma unroll
    for (int k = 0; k < D; ++k) w[k] = W[(wave * D + k) * D + lane];
    __syncthreads();

    for (int r = 0; r < TILE_FR; ++r) {
        const float4* hr = reinterpret_cast<const float4*>(hlds + r * D);
        const float4* ar = reinterpret_cast<const float4*>(alds[wave] + r * D);
        float acc = 0.f;
#pragma unroll
        for (int k4 = 0; k4 < 16; ++k4) {
            float4 v = hr[k4];
            float4 a = ar[k4];
            acc = fmaf(v.x + a.x, w[4 * k4 + 0], acc);
            acc = fmaf(v.y + a.y, w[4 * k4 + 1], acc);
            acc = fmaf(v.z + a.z, w[4 * k4 + 2], acc);
            acc = fmaf(v.w + a.w, w[4 * k4 + 3], acc);
        }
        part[wave][r * D + lane] = sc[wave][r] * acc;
    }
    __syncthreads();
    for (int i = threadIdx.x; i < TILE_FR * D; i += 256) {
        int j = i & 63;
        float b = 0.25f * (bias[j] + bias[64 + j] + bias[128 + j] + bias[192 + j]);
        out[(size_t)row0 * D + i] =
            0.25f * (part[0][i] + part[1][i] + part[2][i] + part[3][i]) + b;
    }
}

// ------------------------- out[dst] += 0.25/(deg+1) * y_c[src]   (atomic)
__global__ void scatter_fwd(const float* __restrict__ y, const int* __restrict__ src,
        const int* __restrict__ dst, const float* __restrict__ deg,
        float* __restrict__ out) {
    int t = blockIdx.x * 256 + threadIdx.x;
    int j = t & 63;
    int idx = t >> 6;
    if (idx >= NCOLS * NE) return;
    int c = idx / NE;
    int s = src[idx];
    int d = dst[idx];
    float scale = 0.25f / (deg[(size_t)c * N_CELL + d] + 1.0f);
    atomicAdd(&out[(size_t)d * D + j],
              scale * y[((size_t)c * N_RID + s) * D + j]);
}

// ------------------------- agg_c[dst] += (h[src] - mu)   (atomic)
__global__ void scatter_rev(const float* __restrict__ h, const int* __restrict__ src,
        const int* __restrict__ dst, const float* __restrict__ mu,
        float* __restrict__ agg) {
    int t = blockIdx.x * 256 + threadIdx.x;
    int j = t & 63;
    int idx = t >> 6;
    if (idx >= NCOLS * NE) return;
    int c = idx / NE;
    int s = src[idx];
    int d = dst[idx];
    float v = h[(size_t)s * D + j];
    if (mu) v -= mu[j];
    atomicAdd(&agg[((size_t)c * N_RID + d) * D + j], v);
}

// ------------------------- column sums (for centering)
__global__ void colsum(const float* __restrict__ x, float* __restrict__ sum, int nrows) {
    __shared__ float p[4][64];
    int j = threadIdx.x & 63, rl = threadIdx.x >> 6;
    float local = 0.f;
    for (int r = blockIdx.x * 4 + rl; r < nrows; r += gridDim.x * 4)
        local += x[(size_t)r * D + j];
    p[rl][j] = local;
    __syncthreads();
    if (rl == 0) atomicAdd(&sum[j], p[0][j] + p[1][j] + p[2][j] + p[3][j]);
}

__global__ void finalize_mean(float* __restrict__ s, float inv_n) {
    s[threadIdx.x] *= inv_n;
}

// ------------------------- combine + center + relu (in place on out)
__global__ void final_combine(float* __restrict__ out, const float* __restrict__ rid,
        const float* __restrict__ mu_c, const float* __restrict__ mu_r) {
    int t = blockIdx.x * 256 + threadIdx.x;
    if (t >= N_CELL * D) return;
    int row = t >> 6, j = t & 63;
    float v = (row < N_RID) ? (rid[(size_t)row * D + j] - mu_r[j])
                            : (out[t] - mu_c[j]);
    out[t] = fmaxf(v, 0.0f);
}

extern "C" void kernel_launch(void* const* d_in, const int* in_sizes, int n_in,
                              void* d_out, int out_size, void* d_ws, size_t ws_size,
                              hipStream_t stream) {
    const float* x_rid  = (const float*)d_in[0];
    const float* x_cell = (const float*)d_in[1];
    const int* src_fwd  = (const int*)d_in[2];
    const int* dst_fwd  = (const int*)d_in[3];
    const int* src_rev  = (const int*)d_in[4];
    const int* dst_rev  = (const int*)d_in[5];
    const float* W1f = (const float*)d_in[6];
    const float* b1f = (const float*)d_in[7];
    const float* W1r = (const float*)d_in[8];
    const float* b1r = (const float*)d_in[9];
    const float* W2f = (const float*)d_in[10];
    const float* b2f = (const float*)d_in[11];
    const float* W2r = (const float*)d_in[12];
    const float* b2r = (const float*)d_in[13];
    float* out = (float*)d_out;

    float* ws    = (float*)d_ws;
    float* rid1  = ws;                                   //  6.4M f32
    float* cell1 = rid1  + (size_t)N_RID * D;            // 25.6M
    float* rid2  = cell1 + (size_t)N_CELL * D;           //  6.4M
    float* yagg  = rid2  + (size_t)N_RID * D;            // 25.6M (y / agg, reused)
    float* degF  = yagg  + (size_t)NCOLS * N_RID * D;    //  1.6M
    float* degR  = degF  + (size_t)NCOLS * N_CELL;       //  0.4M
    float* sums  = degR  + (size_t)NCOLS * N_RID;        //  256

    hipMemsetAsync(degF, 0, (size_t)NCOLS * N_CELL * sizeof(float), stream);
    hipMemsetAsync(degR, 0, (size_t)NCOLS * N_RID * sizeof(float), stream);
    hipMemsetAsync(sums, 0, 256 * sizeof(float), stream);

    int gdeg = (NCOLS * NE + 255) / 256;
    deg_kernel<<<gdeg, 256, 0, stream>>>(dst_fwd, degF, N_CELL);
    deg_kernel<<<gdeg, 256, 0, stream>>>(dst_rev, degR, N_RID);

    const int g_scat = (NCOLS * NE * 64) / 256;   // 100000
    // ---------------- layer 1 (inputs uncentered) ----------------
    y_gemm<<<(N_RID + 63) / 64, 256, 0, stream>>>(x_rid, W1f, nullptr, yagg, N_RID);
    self_cell<<<N_CELL / TILE_SC, 256, 0, stream>>>(x_cell, degF, W1f, b1f, nullptr,
                                                    cell1, N_CELL);
    scatter_fwd<<<g_scat, 256, 0, stream>>>(yagg, src_fwd, dst_fwd, degF, cell1);
    hipMemsetAsync(yagg, 0, (size_t)NCOLS * N_RID * D * sizeof(float), stream);
    scatter_rev<<<g_scat, 256, 0, stream>>>(x_cell, src_rev, dst_rev, nullptr, yagg);
    fused_rid<<<N_RID / TILE_FR, 256, 0, stream>>>(x_rid, yagg, degR, W1r, b1r,
                                                   nullptr, rid1, N_RID);
    colsum<<<1024, 256, 0, stream>>>(cell1, sums + 0, N_CELL);
    colsum<<<1024, 256, 0, stream>>>(rid1, sums + 64, N_RID);
    finalize_mean<<<1, 64, 0, stream>>>(sums + 0, 1.0f / N_CELL);
    finalize_mean<<<1, 64, 0, stream>>>(sums + 64, 1.0f / N_RID);

    // ---------------- layer 2 (subtract layer-1 means at read) ----------------
    y_gemm<<<(N_RID + 63) / 64, 256, 0, stream>>>(rid1, W2f, sums + 64, yagg, N_RID);
    self_cell<<<N_CELL / TILE_SC, 256, 0, stream>>>(cell1, degF, W2f, b2f, sums + 0,
                                                    out, N_CELL);
    scatter_fwd<<<g_scat, 256, 0, stream>>>(yagg, src_fwd, dst_fwd, degF, out);
    hipMemsetAsync(yagg, 0, (size_t)NCOLS * N_RID * D * sizeof(float), stream);
    scatter_rev<<<g_scat, 256, 0, stream>>>(cell1, src_rev, dst_rev, sums + 0, yagg);
    fused_rid<<<N_RID / TILE_FR, 256, 0, stream>>>(rid1, yagg, degR, W2r, b2r,
                                                   sums + 64, rid2, N_RID);
    colsum<<<1024, 256, 0, stream>>>(out, sums + 128, N_CELL);
    colsum<<<1024, 256, 0, stream>>>(rid2, sums + 192, N_RID);
    finalize_mean<<<1, 64, 0, stream>>>(sums + 128, 1.0f / N_CELL);
    finalize_mean<<<1, 64, 0, stream>>>(sums + 192, 1.0f / N_RID);

    final_combine<<<(N_CELL * D) / 256, 256, 0, stream>>>(out, rid2, sums + 128,
                                                          sums + 192);
}